// Round 1
// baseline (1320.709 us; speedup 1.0000x reference)
//
#include <hip/hip_runtime.h>

// Problem constants (B=16, C=3, H=W=512)
#define HW_SHIFT 18
#define HW_ (1 << HW_SHIFT)          // 262144
#define NCH 48                        // B*C
#define TOTAL (NCH * HW_)             // 12,582,912

__device__ __forceinline__ float t2i(float x) { return fmaf(x, 127.5f, 127.5f); }

__device__ __forceinline__ int bin_of(float v, float lo, float invw, int nbins) {
    int b = (int)((v - lo) * invw);
    b = b < 0 ? 0 : b;
    b = b >= nbins ? nbins - 1 : b;
    return b;
}

__global__ __launch_bounds__(256) void hist_kernel(
    const float* __restrict__ tgt, const float* __restrict__ ref,
    const float* __restrict__ smask, const float* __restrict__ tmask,
    unsigned* __restrict__ hist_ref, unsigned* __restrict__ hist_tmpl,
    int nbins, float lo, float invw)
{
    long long stride = (long long)gridDim.x * blockDim.x;
    for (long long idx = (long long)blockIdx.x * blockDim.x + threadIdx.x;
         idx < TOTAL; idx += stride) {
        int ch  = (int)(idx >> HW_SHIFT);      // b*3 + c
        int pix = (int)(idx & (HW_ - 1));
        int b   = ch / 3;
        long long midx = ((long long)b << HW_SHIFT) + pix;
        float sm = smask[midx];
        float tm = tmask[midx];
        float rv = t2i(ref[idx]) * sm;
        float tv = t2i(tgt[idx]) * tm;
        atomicAdd(&hist_ref[ch * nbins + bin_of(rv, lo, invw, nbins)], 1u);
        atomicAdd(&hist_tmpl[ch * nbins + bin_of(tv, lo, invw, nbins)], 1u);
    }
}

template <int T>
__device__ void scan_row(unsigned* __restrict__ row, int nbins) {
    __shared__ unsigned tot[T];
    int t = threadIdx.x;
    int items = nbins / T;
    unsigned* base = row + t * items;
    unsigned run = 0;
    for (int i = 0; i < items; ++i) { run += base[i]; base[i] = run; }
    tot[t] = run;
    __syncthreads();
    // Hillis-Steele inclusive scan of per-thread totals
    for (int off = 1; off < T; off <<= 1) {
        unsigned v = (t >= off) ? tot[t - off] : 0u;
        __syncthreads();
        tot[t] += v;
        __syncthreads();
    }
    unsigned excl = tot[t] - run;
    for (int i = 0; i < items; ++i) base[i] += excl;
}

__global__ __launch_bounds__(256) void scan_kernel(
    unsigned* __restrict__ hist_ref, unsigned* __restrict__ hist_tmpl, int nbins)
{
    int ch = blockIdx.x;
    scan_row<256>(hist_ref + (size_t)ch * nbins, nbins);
    __syncthreads();
    scan_row<256>(hist_tmpl + (size_t)ch * nbins, nbins);
}

__global__ __launch_bounds__(256) void lut_kernel(
    const unsigned* __restrict__ cum_ref, const unsigned* __restrict__ cum_tmpl,
    float* __restrict__ lut, int nbins, float lo, float w)
{
    int stride = gridDim.x * blockDim.x;
    int total = NCH * nbins;
    for (int i = blockIdx.x * blockDim.x + threadIdx.x; i < total; i += stride) {
        int ch  = i / nbins;
        int bin = i - ch * nbins;
        unsigned r    = cum_ref[i];
        unsigned prev = bin ? cum_ref[i - 1] : 0u;
        if (r == prev) { lut[i] = 0.0f; continue; }  // empty ref bin: value unused
        const unsigned* row = cum_tmpl + (size_t)ch * nbins;
        // lower_bound: smallest j with row[j] >= r   (1 <= r <= N guaranteed)
        int loi = 0, hii = nbins;
        while (loi < hii) {
            int mid = (loi + hii) >> 1;
            if (row[mid] < r) loi = mid + 1; else hii = mid;
        }
        int j = loi;
        unsigned cj    = row[j];
        unsigned cprev = j ? row[j - 1] : 0u;
        unsigned cnt   = cj - cprev;                 // >= 1
        float frac = ((float)(r - cprev) - 0.5f) / (float)cnt;  // in (0,1)
        lut[i] = lo + ((float)j + frac) * w;
    }
}

__global__ __launch_bounds__(256) void loss_kernel(
    const float* __restrict__ src, const float* __restrict__ ref,
    const float* __restrict__ smask, const float* __restrict__ lut,
    double* __restrict__ partials, int nbins, float lo, float invw)
{
    double acc = 0.0;
    long long stride = (long long)gridDim.x * blockDim.x;
    for (long long idx = (long long)blockIdx.x * blockDim.x + threadIdx.x;
         idx < TOTAL; idx += stride) {
        int ch  = (int)(idx >> HW_SHIFT);
        int pix = (int)(idx & (HW_ - 1));
        int b   = ch / 3;
        float sm = smask[((long long)b << HW_SHIFT) + pix];
        float rv = t2i(ref[idx]) * sm;               // identical to hist kernel
        float mv = lut[ch * nbins + bin_of(rv, lo, invw, nbins)];
        float d  = sm * (t2i(src[idx]) - mv);        // src*sm - matched*sm
        acc += (double)d * (double)d;
    }
    __shared__ double sred[256];
    sred[threadIdx.x] = acc;
    __syncthreads();
    for (int off = 128; off > 0; off >>= 1) {
        if (threadIdx.x < off) sred[threadIdx.x] += sred[threadIdx.x + off];
        __syncthreads();
    }
    if (threadIdx.x == 0) partials[blockIdx.x] = sred[0];
}

__global__ __launch_bounds__(256) void finalize_kernel(
    const double* __restrict__ partials, int n, float* __restrict__ out)
{
    __shared__ double sred[256];
    double acc = 0.0;
    for (int i = threadIdx.x; i < n; i += 256) acc += partials[i];
    sred[threadIdx.x] = acc;
    __syncthreads();
    for (int off = 128; off > 0; off >>= 1) {
        if (threadIdx.x < off) sred[threadIdx.x] += sred[threadIdx.x + off];
        __syncthreads();
    }
    if (threadIdx.x == 0) out[0] = (float)(sred[0] / (double)TOTAL);
}

extern "C" void kernel_launch(void* const* d_in, const int* in_sizes, int n_in,
                              void* d_out, int out_size, void* d_ws, size_t ws_size,
                              hipStream_t stream) {
    const float* src   = (const float*)d_in[0];
    const float* tgt   = (const float*)d_in[1];
    const float* smask = (const float*)d_in[2];
    const float* tmask = (const float*)d_in[3];
    const float* ref   = (const float*)d_in[4];
    float* out = (float*)d_out;

    const int LOSS_BLOCKS = 3072;

    // workspace layout: [partials | hist_ref | hist_tmpl | lut]
    size_t off = 0;
    double* partials = (double*)d_ws;
    off += (size_t)LOSS_BLOCKS * sizeof(double);
    off = (off + 255) & ~(size_t)255;

    int nbins = 65536;
    while (nbins > 1024 && off + (size_t)3 * NCH * nbins * 4 > ws_size) nbins >>= 1;

    unsigned* hist_ref  = (unsigned*)((char*)d_ws + off); off += (size_t)NCH * nbins * 4;
    unsigned* hist_tmpl = (unsigned*)((char*)d_ws + off); off += (size_t)NCH * nbins * 4;
    float*    lut       = (float*)((char*)d_ws + off);

    const float lo   = -640.0f;
    const float hi   =  896.0f;
    const float w    = (hi - lo) / (float)nbins;
    const float invw = (float)nbins / (hi - lo);

    // zero both histograms (contiguous)
    hipMemsetAsync(hist_ref, 0, (size_t)2 * NCH * nbins * 4, stream);

    hist_kernel<<<2048, 256, 0, stream>>>(tgt, ref, smask, tmask,
                                          hist_ref, hist_tmpl, nbins, lo, invw);
    scan_kernel<<<NCH, 256, 0, stream>>>(hist_ref, hist_tmpl, nbins);
    lut_kernel<<<2048, 256, 0, stream>>>(hist_ref, hist_tmpl, lut, nbins, lo, w);
    loss_kernel<<<LOSS_BLOCKS, 256, 0, stream>>>(src, ref, smask, lut,
                                                 partials, nbins, lo, invw);
    finalize_kernel<<<1, 256, 0, stream>>>(partials, LOSS_BLOCKS, out);
}

// Round 2
// 74.744 us; speedup vs baseline: 17.6698x; 17.6698x over previous
//
#include <hip/hip_runtime.h>

// Problem constants (B=16, C=3, H=W=512)
#define HW_SHIFT 18
#define HW_ (1 << HW_SHIFT)           // 262144
#define NCH 48                         // B*C
#define NTASK (2 * NCH)                // 96: ref-hist and tgt-hist per channel
#define TOTAL (NCH * HW_)              // 12,582,912
#define NBINS 8192                     // 32KB LDS histogram
#define LO_ (-640.0f)
#define HI_ (896.0f)
#define BINW ((HI_ - LO_) / (float)NBINS)
#define INVW ((float)NBINS / (HI_ - LO_))
#define LOSS_BLOCKS 1024

__device__ __forceinline__ float t2i(float x) { return fmaf(x, 127.5f, 127.5f); }

__device__ __forceinline__ int bin_of(float v) {
    int b = (int)((v - LO_) * INVW);
    b = b < 0 ? 0 : b;
    b = b > NBINS - 1 ? NBINS - 1 : b;
    return b;
}

// grid = NTASK*bpt blocks. task = blockIdx.x/bpt; which = task/NCH (0=ref/smask,
// 1=tgt/tmask); ch = task%NCH. Each block histograms HW_/bpt pixels into LDS,
// then plain-stores the 8192-bin partial (no global atomics).
__global__ __launch_bounds__(256) void hist_kernel(
    const float* __restrict__ ref, const float* __restrict__ tgt,
    const float* __restrict__ smask, const float* __restrict__ tmask,
    unsigned* __restrict__ partials, int bpt)
{
    __shared__ unsigned lh[NBINS];
    for (int i = threadIdx.x; i < NBINS; i += 256) lh[i] = 0u;
    __syncthreads();

    int task  = blockIdx.x / bpt;
    int slice = blockIdx.x - task * bpt;
    int which = task / NCH;
    int ch    = task - which * NCH;
    const float* img = which ? tgt : ref;
    const float* msk = which ? tmask : smask;
    int mb = ch / 3;

    const float4* img4 = (const float4*)img + ((size_t)ch << (HW_SHIFT - 2));
    const float4* msk4 = (const float4*)msk + ((size_t)mb << (HW_SHIFT - 2));
    int n4   = (HW_ / 4) / bpt;
    int base = slice * n4;
    for (int i = threadIdx.x; i < n4; i += 256) {
        float4 v = img4[base + i];
        float4 m = msk4[base + i];
        atomicAdd(&lh[bin_of(t2i(v.x) * m.x)], 1u);
        atomicAdd(&lh[bin_of(t2i(v.y) * m.y)], 1u);
        atomicAdd(&lh[bin_of(t2i(v.z) * m.z)], 1u);
        atomicAdd(&lh[bin_of(t2i(v.w) * m.w)], 1u);
    }
    __syncthreads();
    unsigned* outp = partials + (size_t)blockIdx.x * NBINS;
    for (int i = threadIdx.x; i < NBINS; i += 256) outp[i] = lh[i];
}

// hist2[t*NBINS+b] = sum over bpt slices. Rows 0..47 = ref hists, 48..95 = tmpl.
__global__ __launch_bounds__(256) void merge_kernel(
    const unsigned* __restrict__ partials, unsigned* __restrict__ hist2, int bpt)
{
    int i = blockIdx.x * 256 + threadIdx.x;
    if (i >= NTASK * NBINS) return;
    int task = i / NBINS;
    int bin  = i - task * NBINS;
    unsigned s = 0;
    for (int k = 0; k < bpt; ++k)
        s += partials[((size_t)(task * bpt + k)) * NBINS + bin];
    hist2[i] = s;
}

template <int T>
__device__ void scan_row(unsigned* __restrict__ row) {
    __shared__ unsigned tot[T];
    int t = threadIdx.x;
    const int items = NBINS / T;
    unsigned* base = row + t * items;
    unsigned run = 0;
    for (int i = 0; i < items; ++i) { run += base[i]; base[i] = run; }
    tot[t] = run;
    __syncthreads();
    for (int off = 1; off < T; off <<= 1) {
        unsigned v = (t >= off) ? tot[t - off] : 0u;
        __syncthreads();
        tot[t] += v;
        __syncthreads();
    }
    unsigned excl = tot[t] - run;
    for (int i = 0; i < items; ++i) base[i] += excl;
}

// grid = NTASK blocks, one cumulative row per block.
__global__ __launch_bounds__(256) void scan_kernel(unsigned* __restrict__ hist2)
{
    scan_row<256>(hist2 + (size_t)blockIdx.x * NBINS);
}

__global__ __launch_bounds__(256) void lut_kernel(
    const unsigned* __restrict__ hist2, float* __restrict__ lut)
{
    int stride = gridDim.x * blockDim.x;
    const int total = NCH * NBINS;
    for (int i = blockIdx.x * 256 + threadIdx.x; i < total; i += stride) {
        int ch  = i / NBINS;
        int bin = i - ch * NBINS;
        unsigned r    = hist2[i];                    // cum_ref row ch
        unsigned prev = bin ? hist2[i - 1] : 0u;
        if (r == prev) { lut[i] = 0.0f; continue; }  // empty ref bin: unused
        const unsigned* row = hist2 + (size_t)(NCH + ch) * NBINS;  // cum_tmpl
        int loi = 0, hii = NBINS;                    // lower_bound(row, r)
        while (loi < hii) {
            int mid = (loi + hii) >> 1;
            if (row[mid] < r) loi = mid + 1; else hii = mid;
        }
        int j = loi;
        unsigned cj    = row[j];
        unsigned cprev = j ? row[j - 1] : 0u;
        unsigned cnt   = cj - cprev;                 // >= 1
        float frac = ((float)(r - cprev) - 0.5f) / (float)cnt;
        lut[i] = LO_ + ((float)j + frac) * BINW;
    }
}

__global__ __launch_bounds__(256) void loss_kernel(
    const float* __restrict__ src, const float* __restrict__ ref,
    const float* __restrict__ smask, const float* __restrict__ lut,
    double* __restrict__ partials)
{
    const float4* src4 = (const float4*)src;
    const float4* ref4 = (const float4*)ref;
    const float4* sm4  = (const float4*)smask;
    const int N4 = TOTAL / 4;
    int stride = gridDim.x * blockDim.x;
    double acc = 0.0;
    for (int i = blockIdx.x * 256 + threadIdx.x; i < N4; i += stride) {
        int ch = i >> (HW_SHIFT - 2);
        int p4 = i & ((HW_ >> 2) - 1);
        int mb = ch / 3;
        float4 m  = sm4[((size_t)mb << (HW_SHIFT - 2)) + p4];
        float4 rv = ref4[i];
        float4 sv = src4[i];
        const float* lrow = lut + (size_t)ch * NBINS;
        float d0 = m.x * (t2i(sv.x) - lrow[bin_of(t2i(rv.x) * m.x)]);
        float d1 = m.y * (t2i(sv.y) - lrow[bin_of(t2i(rv.y) * m.y)]);
        float d2 = m.z * (t2i(sv.z) - lrow[bin_of(t2i(rv.z) * m.z)]);
        float d3 = m.w * (t2i(sv.w) - lrow[bin_of(t2i(rv.w) * m.w)]);
        acc += (double)d0 * d0 + (double)d1 * d1
             + (double)d2 * d2 + (double)d3 * d3;
    }
    __shared__ double sred[256];
    sred[threadIdx.x] = acc;
    __syncthreads();
    for (int off = 128; off > 0; off >>= 1) {
        if (threadIdx.x < off) sred[threadIdx.x] += sred[threadIdx.x + off];
        __syncthreads();
    }
    if (threadIdx.x == 0) partials[blockIdx.x] = sred[0];
}

__global__ __launch_bounds__(256) void finalize_kernel(
    const double* __restrict__ partials, int n, float* __restrict__ out)
{
    __shared__ double sred[256];
    double acc = 0.0;
    for (int i = threadIdx.x; i < n; i += 256) acc += partials[i];
    sred[threadIdx.x] = acc;
    __syncthreads();
    for (int off = 128; off > 0; off >>= 1) {
        if (threadIdx.x < off) sred[threadIdx.x] += sred[threadIdx.x + off];
        __syncthreads();
    }
    if (threadIdx.x == 0) out[0] = (float)(sred[0] / (double)TOTAL);
}

extern "C" void kernel_launch(void* const* d_in, const int* in_sizes, int n_in,
                              void* d_out, int out_size, void* d_ws, size_t ws_size,
                              hipStream_t stream) {
    const float* src   = (const float*)d_in[0];
    const float* tgt   = (const float*)d_in[1];
    const float* smask = (const float*)d_in[2];
    const float* tmask = (const float*)d_in[3];
    const float* ref   = (const float*)d_in[4];
    float* out = (float*)d_out;

    // workspace: [loss partials | hist2 | lut | slice partials]
    size_t off = 0;
    double* lpart = (double*)d_ws;
    off += (size_t)LOSS_BLOCKS * sizeof(double);
    off = (off + 255) & ~(size_t)255;
    unsigned* hist2 = (unsigned*)((char*)d_ws + off);
    off += (size_t)NTASK * NBINS * 4;
    float* lut = (float*)((char*)d_ws + off);
    off += (size_t)NCH * NBINS * 4;

    int bpt = 8;  // 768 blocks = 3/CU exactly; fall back if workspace small
    while (bpt > 1 && off + (size_t)NTASK * bpt * NBINS * 4 > ws_size) bpt >>= 1;
    unsigned* partials = (unsigned*)((char*)d_ws + off);

    hist_kernel<<<NTASK * bpt, 256, 0, stream>>>(ref, tgt, smask, tmask,
                                                 partials, bpt);
    merge_kernel<<<(NTASK * NBINS + 255) / 256, 256, 0, stream>>>(partials,
                                                                  hist2, bpt);
    scan_kernel<<<NTASK, 256, 0, stream>>>(hist2);
    lut_kernel<<<(NCH * NBINS + 255) / 256, 256, 0, stream>>>(hist2, lut);
    loss_kernel<<<LOSS_BLOCKS, 256, 0, stream>>>(src, ref, smask, lut, lpart);
    finalize_kernel<<<1, 256, 0, stream>>>(lpart, LOSS_BLOCKS, out);
}